// Round 1
// baseline (2304.639 us; speedup 1.0000x reference)
//
#include <hip/hip_runtime.h>
#include <cstdint>
#include <cstddef>

// ---------- types ----------
using short8_t = __attribute__((ext_vector_type(8))) short;
using f32x4    = __attribute__((ext_vector_type(4))) float;
typedef unsigned short bfu16;

constexpr int   Nn   = 16;
constexpr int   Tt   = 1024;
constexpr int   IDIM = 512;
constexpr int   Vv   = 4096;
constexpr int   Ss   = 128;
constexpr int   Ll   = 2 * Ss + 1;   // 257
constexpr int   LS   = 132;          // lablog row stride (pad 129 -> 132)
constexpr float NEGV = -1e30f;

// ---------- helpers ----------
__device__ __forceinline__ bfu16 f2bf(float f) {
  unsigned int x = __float_as_uint(f);
  x = x + 0x7fffu + ((x >> 16) & 1u);   // RNE (inputs are finite normals)
  return (bfu16)(x >> 16);
}

__device__ __forceinline__ void async16(const void* g, void* l) {
  __builtin_amdgcn_global_load_lds(
      (__attribute__((address_space(1))) void*)(g),
      (__attribute__((address_space(3))) void*)(l), 16, 0, 0);
}

__device__ __forceinline__ float lae(float x, float y) {
  float m = fmaxf(x, y);
  float d = fminf(x, y) - m;            // <= 0
  return m + log1pf(__expf(d));
}

// ---------- kernel 1: fp32 -> bf16 convert + zero output ----------
__global__ void convert_zero(const float4* __restrict__ hs4,
                             const float4* __restrict__ W4,
                             ushort4* __restrict__ hsb4,
                             ushort4* __restrict__ Wb4,
                             float* __restrict__ out) {
  if (blockIdx.x == 0 && threadIdx.x == 0) out[0] = 0.f;
  const int HS4 = (Nn * Tt * IDIM) / 4;        // 2097152
  const int TOT = HS4 + (Vv * IDIM) / 4;       // +524288
  for (int i = blockIdx.x * 256 + threadIdx.x; i < TOT; i += gridDim.x * 256) {
    float4 f;
    if (i < HS4) f = hs4[i]; else f = W4[i - HS4];
    ushort4 o;
    o.x = f2bf(f.x); o.y = f2bf(f.y); o.z = f2bf(f.z); o.w = f2bf(f.w);
    if (i < HS4) hsb4[i] = o; else Wb4[i - HS4] = o;
  }
}

// ---------- kernel 2: build label map / extended sequence ----------
__global__ void build_labels(const int* __restrict__ ys,
                             int* __restrict__ labmap,
                             int* __restrict__ extidx,
                             int* __restrict__ skipflag) {
  const int n = blockIdx.x, tid = threadIdx.x;
  int* lm = labmap + n * Vv;
  for (int v = tid; v < Vv; v += 256) lm[v] = 0x7fffffff;
  __syncthreads();
  if (tid == 0) lm[0] = 0;                                  // blank -> slot 0
  if (tid < Ss) atomicMin(&lm[ys[n * Ss + tid]], tid + 1);  // canonical = first occurrence
  __syncthreads();
  for (int s = tid; s < Ll; s += 256) {
    int v = (s & 1) ? ys[n * Ss + ((s - 1) >> 1)] : 0;
    extidx[n * Ll + s] = lm[v];
    int allow = 0;
    if ((s & 1) && s >= 3) allow = (v != ys[n * Ss + ((s - 3) >> 1)]) ? 1 : 0;
    skipflag[n * Ll + s] = allow;
  }
  __syncthreads();
  for (int v = tid; v < Vv; v += 256)
    if (lm[v] == 0x7fffffff) lm[v] = -1;
}

// ---------- kernel 3: bf16 MFMA GEMM fused with lse partials + label scatter ----------
__global__ __launch_bounds__(256) void gemm_lse(
    const bfu16* __restrict__ A,      // [16384][512] hs bf16
    const bfu16* __restrict__ B,      // [4096][512]  W  bf16 (B^T layout)
    const float* __restrict__ bias,   // [4096]
    const int*   __restrict__ labmap, // [16][4096]
    float* __restrict__ lablog,       // [16384][LS]
    float* __restrict__ pmax,         // [64][16384]
    float* __restrict__ psum) {       // [64][16384]
  __shared__ bfu16 ldsA[128 * 32];    // 8 KB
  __shared__ bfu16 ldsB[128 * 32];    // 8 KB
  const int bR = blockIdx.x, bC = blockIdx.y;
  const int rowbase = bR * 128, colbase = bC * 128;
  const int tid  = threadIdx.x;
  const int lane = tid & 63, wid = tid >> 6;
  const int wr = wid >> 1, wc = wid & 1;

  f32x4 acc[4][4];
#pragma unroll
  for (int m = 0; m < 4; m++)
#pragma unroll
    for (int n = 0; n < 4; n++) {
      f32x4 z = {0.f, 0.f, 0.f, 0.f};
      acc[m][n] = z;
    }

  // staging: wave w owns rows [w*32, w*32+32) of each tile; 2 x 1KB issues per tile
  const int r16 = lane >> 2;              // 0..15
  const int cb  = (lane & 3) * 16;        // byte offset within 64B row
  const char* gA0 = (const char*)(A + (size_t)(rowbase + wid * 32 + r16) * IDIM) + cb;
  const char* gB0 = (const char*)(B + (size_t)(colbase + wid * 32 + r16) * IDIM) + cb;
  char* dA = (char*)ldsA + wid * 2048;
  char* dB = (char*)ldsB + wid * 2048;

  const int fr  = lane & 15;
  const int fkB = (lane >> 4) * 16;       // byte offset of lane's 8 contiguous k

  for (int k0 = 0; k0 < IDIM; k0 += 32) {
    const char* ga = gA0 + k0 * 2;
    const char* gb = gB0 + k0 * 2;
    async16(ga,          dA);
    async16(ga + 16384,  dA + 1024);      // +16 rows (16*512*2 bytes)
    async16(gb,          dB);
    async16(gb + 16384,  dB + 1024);
    __syncthreads();                      // drains vmcnt before reads

    short8_t af[4], bfr[4];
#pragma unroll
    for (int m = 0; m < 4; m++)
      af[m] = *(const short8_t*)((const char*)ldsA + (wr * 64 + m * 16 + fr) * 64 + fkB);
#pragma unroll
    for (int n = 0; n < 4; n++)
      bfr[n] = *(const short8_t*)((const char*)ldsB + (wc * 64 + n * 16 + fr) * 64 + fkB);

#pragma unroll
    for (int m = 0; m < 4; m++)
#pragma unroll
      for (int n = 0; n < 4; n++)
        acc[m][n] = __builtin_amdgcn_mfma_f32_16x16x32_bf16(af[m], bfr[n], acc[m][n], 0, 0, 0);
    __syncthreads();                      // protect LDS before next stage
  }

  // ---- epilogue: bias, label scatter, row-wise max/sumexp partials ----
  const int nsamp = bR >> 3;              // 8 row-tiles per sample
  const int* lm = labmap + nsamp * Vv;
  const int g4 = (lane >> 4) * 4;

  float bc[4];
  int   slot[4];
#pragma unroll
  for (int n = 0; n < 4; n++) {
    int c = colbase + wc * 64 + n * 16 + fr;
    bc[n]   = bias[c];
    slot[n] = lm[c];
  }

#pragma unroll
  for (int m = 0; m < 4; m++) {
#pragma unroll
    for (int r = 0; r < 4; r++) {
      int row = rowbase + wr * 64 + m * 16 + g4 + r;
      float v0 = acc[m][0][r] + bc[0];
      float v1 = acc[m][1][r] + bc[1];
      float v2 = acc[m][2][r] + bc[2];
      float v3 = acc[m][3][r] + bc[3];
      if (slot[0] >= 0) lablog[(size_t)row * LS + slot[0]] = v0;
      if (slot[1] >= 0) lablog[(size_t)row * LS + slot[1]] = v1;
      if (slot[2] >= 0) lablog[(size_t)row * LS + slot[2]] = v2;
      if (slot[3] >= 0) lablog[(size_t)row * LS + slot[3]] = v3;
      float mx = fmaxf(fmaxf(v0, v1), fmaxf(v2, v3));
      float sm = __expf(v0 - mx) + __expf(v1 - mx) + __expf(v2 - mx) + __expf(v3 - mx);
#pragma unroll
      for (int off = 1; off < 16; off <<= 1) {
        float om = __shfl_xor(mx, off);
        float os = __shfl_xor(sm, off);
        float nm = fmaxf(mx, om);
        sm = sm * __expf(mx - nm) + os * __expf(om - nm);
        mx = nm;
      }
      if (fr == 0) {
        int pc = bC * 2 + wc;             // 0..63
        pmax[(size_t)pc * 16384 + row] = mx;
        psum[(size_t)pc * 16384 + row] = sm;
      }
    }
  }
}

// ---------- kernel 4: reduce 64 lse partials per row ----------
__global__ void lse_reduce(const float* __restrict__ pmax,
                           const float* __restrict__ psum,
                           float* __restrict__ lse) {
  int row = blockIdx.x * 256 + threadIdx.x;
  float m = NEGV, s = 0.f;
#pragma unroll 8
  for (int j = 0; j < 64; j++) {
    float pm = pmax[(size_t)j * 16384 + row];
    float ps = psum[(size_t)j * 16384 + row];
    float nm = fmaxf(m, pm);
    s = s * __expf(m - nm) + ps * __expf(pm - nm);
    m = nm;
  }
  lse[row] = m + __logf(s);
}

// ---------- kernel 5: CTC forward DP, one wave per sample ----------
__global__ __launch_bounds__(64) void ctc_dp(
    const float* __restrict__ lablog, const float* __restrict__ lse,
    const int* __restrict__ extidx, const int* __restrict__ skipflag,
    const int* __restrict__ hlens, const int* __restrict__ ylens,
    float* __restrict__ out) {
  const int n    = blockIdx.x;
  const int lane = threadIdx.x;
  const int hlen = hlens[n];
  const int Ln   = 2 * ylens[n] + 1;
  const int sbase = lane * 4;
  const bool has5 = (lane == 63);         // lane 63 also owns s=256

  int  eidx[5];
  bool skf[5], msk[5];
#pragma unroll
  for (int j = 0; j < 5; j++) {
    bool ok = (j < 4) || has5;
    int  s  = sbase + j;
    int  ss = ok ? s : 0;
    eidx[j] = extidx[n * Ll + ss];
    skf[j]  = skipflag[n * Ll + ss] != 0;
    msk[j]  = ok && (s < Ln);
  }

  const float* ll  = lablog + (size_t)n * Tt * LS;
  const float* lsp = lse + n * Tt;

  float a[5];
  {
    float lse0 = lsp[0];
#pragma unroll
    for (int j = 0; j < 5; j++) {
      int s = sbase + j;
      a[j] = (s <= 1) ? (ll[eidx[j]] - lse0) : NEGV;
    }
  }

  // software prefetch of next row
  float plp[5], plse;
  plse = lsp[1];
#pragma unroll
  for (int j = 0; j < 5; j++) plp[j] = ll[(size_t)LS + eidx[j]];

  for (int t = 1; t < hlen; ++t) {
    float lp[5];
    float lst = plse;
#pragma unroll
    for (int j = 0; j < 5; j++) lp[j] = plp[j];
    int tn = (t + 1 < Tt) ? (t + 1) : t;
    plse = lsp[tn];
#pragma unroll
    for (int j = 0; j < 5; j++) plp[j] = ll[(size_t)tn * LS + eidx[j]];

    float prev3 = __shfl_up(a[3], 1);     // a[sbase-1]
    float prev2 = __shfl_up(a[2], 1);     // a[sbase-2]
    if (lane == 0) { prev3 = NEGV; prev2 = NEGV; }

    float na[5];
#pragma unroll
    for (int j = 0; j < 5; j++) {
      float a2 = (j >= 1) ? a[j - 1] : prev3;
      float a3 = (j >= 2) ? a[j - 2] : ((j == 1) ? prev3 : prev2);
      float r  = lae(a[j], a2);
      float a3v = skf[j] ? a3 : NEGV;
      r = lae(r, a3v);
      float v = r + (lp[j] - lst);
      na[j] = msk[j] ? v : NEGV;
    }
#pragma unroll
    for (int j = 0; j < 5; j++) a[j] = na[j];
  }

  __shared__ float alf[264];
#pragma unroll
  for (int j = 0; j < 4; j++) alf[sbase + j] = a[j];
  if (has5) alf[256] = a[4];
  __syncthreads();
  if (lane == 0) {
    float e1 = alf[Ln - 1];
    float e2 = alf[Ln - 2];
    float m  = fmaxf(e1, e2);
    float llv = m + log1pf(__expf(fminf(e1, e2) - m));
    float per = (llv > -1e29f) ? -llv : 0.f;
    atomicAdd(out, per * (1.0f / 16.0f));
  }
}

// ---------- launcher ----------
extern "C" void kernel_launch(void* const* d_in, const int* in_sizes, int n_in,
                              void* d_out, int out_size, void* d_ws, size_t ws_size,
                              hipStream_t stream) {
  const float* hs    = (const float*)d_in[0];
  const int*   hlens = (const int*)d_in[1];
  const int*   ys    = (const int*)d_in[2];
  const int*   ylens = (const int*)d_in[3];
  const float* W     = (const float*)d_in[4];
  const float* bias  = (const float*)d_in[5];
  float*       out   = (float*)d_out;
  char*        ws    = (char*)d_ws;

  // workspace carve (bytes)
  const size_t off_hsb    = 0;                               // 16,777,216
  const size_t off_Wb     = off_hsb    + (size_t)Nn*Tt*IDIM*2;
  const size_t off_lablog = off_Wb     + (size_t)Vv*IDIM*2;  // 8,650,752
  const size_t off_pmax   = off_lablog + (size_t)Nn*Tt*LS*4;
  const size_t off_psum   = off_pmax   + (size_t)64*16384*4;
  const size_t off_lse    = off_psum   + (size_t)64*16384*4;
  const size_t off_labmap = off_lse    + (size_t)16384*4;
  const size_t off_extidx = off_labmap + (size_t)Nn*Vv*4;
  const size_t off_skip   = off_extidx + (size_t)((Nn*Ll*4 + 255) & ~255);

  bfu16* hsb    = (bfu16*)(ws + off_hsb);
  bfu16* Wb     = (bfu16*)(ws + off_Wb);
  float* lablog = (float*)(ws + off_lablog);
  float* pmax   = (float*)(ws + off_pmax);
  float* psum   = (float*)(ws + off_psum);
  float* lse    = (float*)(ws + off_lse);
  int*   labmap = (int*)(ws + off_labmap);
  int*   extidx = (int*)(ws + off_extidx);
  int*   skipf  = (int*)(ws + off_skip);

  convert_zero<<<2048, 256, 0, stream>>>(
      (const float4*)hs, (const float4*)W, (ushort4*)hsb, (ushort4*)Wb, out);
  build_labels<<<16, 256, 0, stream>>>(ys, labmap, extidx, skipf);
  gemm_lse<<<dim3(128, 32), 256, 0, stream>>>(hsb, Wb, bias, labmap, lablog, pmax, psum);
  lse_reduce<<<64, 256, 0, stream>>>(pmax, psum, lse);
  ctc_dp<<<16, 64, 0, stream>>>(lablog, lse, extidx, skipf, hlens, ylens, out);
}

// Round 3
// 320.901 us; speedup vs baseline: 7.1818x; 7.1818x over previous
//
#include <hip/hip_runtime.h>
#include <cstdint>
#include <cstddef>

// ---------- types ----------
using short8_t = __attribute__((ext_vector_type(8))) short;
using f32x4    = __attribute__((ext_vector_type(4))) float;
typedef unsigned short bfu16;

constexpr int   Nn   = 16;
constexpr int   Tt   = 1024;
constexpr int   IDIM = 512;
constexpr int   Vv   = 4096;
constexpr int   Ss   = 128;
constexpr int   Ll   = 2 * Ss + 1;   // 257
constexpr int   LS   = 132;          // lablog row stride (pad 129 -> 132)
constexpr float NEGV = -1e30f;

// ---------- helpers ----------
__device__ __forceinline__ float fexp2(float x) { return __builtin_amdgcn_exp2f(x); }
__device__ __forceinline__ float flog2(float x) { return __builtin_amdgcn_logf(x); }

__device__ __forceinline__ bfu16 f2bf(float f) {
  unsigned int x = __float_as_uint(f);
  x = x + 0x7fffu + ((x >> 16) & 1u);   // RNE (inputs are finite normals)
  return (bfu16)(x >> 16);
}

__device__ __forceinline__ void async16(const void* g, void* l) {
  __builtin_amdgcn_global_load_lds(
      (__attribute__((address_space(1))) void*)(g),
      (__attribute__((address_space(3))) void*)(l), 16, 0, 0);
}

// ---------- kernel 1: fp32 -> bf16 convert + zero output ----------
__global__ void convert_zero(const float4* __restrict__ hs4,
                             const float4* __restrict__ W4,
                             ushort4* __restrict__ hsb4,
                             ushort4* __restrict__ Wb4,
                             float* __restrict__ out) {
  if (blockIdx.x == 0 && threadIdx.x == 0) out[0] = 0.f;
  const int HS4 = (Nn * Tt * IDIM) / 4;        // 2097152
  const int TOT = HS4 + (Vv * IDIM) / 4;       // +524288
  for (int i = blockIdx.x * 256 + threadIdx.x; i < TOT; i += gridDim.x * 256) {
    float4 f;
    if (i < HS4) f = hs4[i]; else f = W4[i - HS4];
    ushort4 o;
    o.x = f2bf(f.x); o.y = f2bf(f.y); o.z = f2bf(f.z); o.w = f2bf(f.w);
    if (i < HS4) hsb4[i] = o; else Wb4[i - HS4] = o;
  }
}

// ---------- kernel 2: build label map / extended sequence ----------
__global__ void build_labels(const int* __restrict__ ys,
                             int* __restrict__ labmap,
                             int* __restrict__ extidx,
                             int* __restrict__ skipflag) {
  const int n = blockIdx.x, tid = threadIdx.x;
  int* lm = labmap + n * Vv;
  for (int v = tid; v < Vv; v += 256) lm[v] = 0x7fffffff;
  __syncthreads();
  if (tid == 0) lm[0] = 0;                                  // blank -> slot 0
  if (tid < Ss) atomicMin(&lm[ys[n * Ss + tid]], tid + 1);  // canonical = first occurrence
  __syncthreads();
  for (int s = tid; s < Ll; s += 256) {
    int v = (s & 1) ? ys[n * Ss + ((s - 1) >> 1)] : 0;
    extidx[n * Ll + s] = lm[v];
    int allow = 0;
    if ((s & 1) && s >= 3) allow = (v != ys[n * Ss + ((s - 3) >> 1)]) ? 1 : 0;
    skipflag[n * Ll + s] = allow;
  }
  __syncthreads();
  for (int v = tid; v < Vv; v += 256)
    if (lm[v] == 0x7fffffff) lm[v] = -1;
}

// ---------- kernel 3: bf16 MFMA GEMM fused with lse partials + label scatter ----------
__global__ __launch_bounds__(256) void gemm_lse(
    const bfu16* __restrict__ A,      // [16384][512] hs bf16
    const bfu16* __restrict__ B,      // [4096][512]  W  bf16 (B^T layout)
    const float* __restrict__ bias,   // [4096]
    const int*   __restrict__ labmap, // [16][4096]
    float* __restrict__ lablog,       // [16384][LS]
    float* __restrict__ pmax,         // [64][16384]
    float* __restrict__ psum) {       // [64][16384]
  __shared__ bfu16 ldsA[128 * 32];    // 8 KB
  __shared__ bfu16 ldsB[128 * 32];    // 8 KB
  const int bR = blockIdx.x, bC = blockIdx.y;
  const int rowbase = bR * 128, colbase = bC * 128;
  const int tid  = threadIdx.x;
  const int lane = tid & 63, wid = tid >> 6;
  const int wr = wid >> 1, wc = wid & 1;

  f32x4 acc[4][4];
#pragma unroll
  for (int m = 0; m < 4; m++)
#pragma unroll
    for (int n = 0; n < 4; n++) {
      f32x4 z = {0.f, 0.f, 0.f, 0.f};
      acc[m][n] = z;
    }

  // staging: wave w owns rows [w*32, w*32+32) of each tile; 2 x 1KB issues per tile
  const int r16 = lane >> 2;              // 0..15
  const int cb  = (lane & 3) * 16;        // byte offset within 64B row
  const char* gA0 = (const char*)(A + (size_t)(rowbase + wid * 32 + r16) * IDIM) + cb;
  const char* gB0 = (const char*)(B + (size_t)(colbase + wid * 32 + r16) * IDIM) + cb;
  char* dA = (char*)ldsA + wid * 2048;
  char* dB = (char*)ldsB + wid * 2048;

  const int fr  = lane & 15;
  const int fkB = (lane >> 4) * 16;       // byte offset of lane's 8 contiguous k

  for (int k0 = 0; k0 < IDIM; k0 += 32) {
    const char* ga = gA0 + k0 * 2;
    const char* gb = gB0 + k0 * 2;
    async16(ga,          dA);
    async16(ga + 16384,  dA + 1024);      // +16 rows (16*512*2 bytes)
    async16(gb,          dB);
    async16(gb + 16384,  dB + 1024);
    __syncthreads();                      // drains vmcnt before reads

    short8_t af[4], bfr[4];
#pragma unroll
    for (int m = 0; m < 4; m++)
      af[m] = *(const short8_t*)((const char*)ldsA + (wr * 64 + m * 16 + fr) * 64 + fkB);
#pragma unroll
    for (int n = 0; n < 4; n++)
      bfr[n] = *(const short8_t*)((const char*)ldsB + (wc * 64 + n * 16 + fr) * 64 + fkB);

#pragma unroll
    for (int m = 0; m < 4; m++)
#pragma unroll
      for (int n = 0; n < 4; n++)
        acc[m][n] = __builtin_amdgcn_mfma_f32_16x16x32_bf16(af[m], bfr[n], acc[m][n], 0, 0, 0);
    __syncthreads();                      // protect LDS before next stage
  }

  // ---- epilogue: bias, label scatter, row-wise max/sumexp partials ----
  const int nsamp = bR >> 3;              // 8 row-tiles per sample
  const int* lm = labmap + nsamp * Vv;
  const int g4 = (lane >> 4) * 4;

  float bc[4];
  int   slot[4];
#pragma unroll
  for (int n = 0; n < 4; n++) {
    int c = colbase + wc * 64 + n * 16 + fr;
    bc[n]   = bias[c];
    slot[n] = lm[c];
  }

#pragma unroll
  for (int m = 0; m < 4; m++) {
#pragma unroll
    for (int r = 0; r < 4; r++) {
      int row = rowbase + wr * 64 + m * 16 + g4 + r;
      float v0 = acc[m][0][r] + bc[0];
      float v1 = acc[m][1][r] + bc[1];
      float v2 = acc[m][2][r] + bc[2];
      float v3 = acc[m][3][r] + bc[3];
      if (slot[0] >= 0) lablog[(size_t)row * LS + slot[0]] = v0;
      if (slot[1] >= 0) lablog[(size_t)row * LS + slot[1]] = v1;
      if (slot[2] >= 0) lablog[(size_t)row * LS + slot[2]] = v2;
      if (slot[3] >= 0) lablog[(size_t)row * LS + slot[3]] = v3;
      float mx = fmaxf(fmaxf(v0, v1), fmaxf(v2, v3));
      float sm = __expf(v0 - mx) + __expf(v1 - mx) + __expf(v2 - mx) + __expf(v3 - mx);
#pragma unroll
      for (int off = 1; off < 16; off <<= 1) {
        float om = __shfl_xor(mx, off);
        float os = __shfl_xor(sm, off);
        float nm = fmaxf(mx, om);
        sm = sm * __expf(mx - nm) + os * __expf(om - nm);
        mx = nm;
      }
      if (fr == 0) {
        int pc = bC * 2 + wc;             // 0..63
        pmax[(size_t)pc * 16384 + row] = mx;
        psum[(size_t)pc * 16384 + row] = sm;
      }
    }
  }
}

// ---------- kernel 4: reduce 64 lse partials per row ----------
__global__ void lse_reduce(const float* __restrict__ pmax,
                           const float* __restrict__ psum,
                           float* __restrict__ lse) {
  int row = blockIdx.x * 256 + threadIdx.x;
  float m = NEGV, s = 0.f;
#pragma unroll 8
  for (int j = 0; j < 64; j++) {
    float pm = pmax[(size_t)j * 16384 + row];
    float ps = psum[(size_t)j * 16384 + row];
    float nm = fmaxf(m, pm);
    s = s * __expf(m - nm) + ps * __expf(pm - nm);
    m = nm;
  }
  lse[row] = m + __logf(s);
}

// ---------- kernel 5: CTC forward DP, one wave per sample ----------
// log2-domain, lse hoisted out of the loop, depth-8 register prefetch ring.
constexpr int DPD = 8;   // prefetch depth

__global__ __launch_bounds__(64) void ctc_dp(
    const float* __restrict__ lablog, const float* __restrict__ lse,
    const int* __restrict__ extidx, const int* __restrict__ skipflag,
    const int* __restrict__ hlens, const int* __restrict__ ylens,
    float* __restrict__ out) {
  const int n    = blockIdx.x;
  const int lane = threadIdx.x;
  const int hlen = hlens[n];
  const int Ln   = 2 * ylens[n] + 1;
  const int sbase = lane * 4;
  const bool has5 = (lane == 63);         // lane 63 also owns s=256
  constexpr float L2E = 1.4426950408889634f;  // log2(e)
  constexpr float LN2 = 0.6931471805599453f;  // ln(2)

  int  eidx[5];
  bool skf[5], msk[5];
#pragma unroll
  for (int j = 0; j < 5; j++) {
    bool ok = (j < 4) || has5;
    int  s  = sbase + j;
    int  ss = ok ? s : 0;
    eidx[j] = extidx[n * Ll + ss];
    skf[j]  = skipflag[n * Ll + ss] != 0;
    msk[j]  = ok && (s < Ln);
  }

  const float* ll  = lablog + (size_t)n * Tt * LS;
  const float* lsp = lse + n * Tt;

  // sum of lse over t < hlen (uniform across states -> hoisted out of the DP)
  float slse = 0.f;
  for (int t = lane; t < hlen; t += 64) slse += lsp[t];
#pragma unroll
  for (int off = 32; off; off >>= 1) slse += __shfl_xor(slse, off);

  // alpha in log2 units of raw logits (no lse subtraction inside the loop)
  float a[5];
#pragma unroll
  for (int j = 0; j < 5; j++) {
    int s = sbase + j;
    a[j] = (s <= 1) ? ll[eidx[j]] * L2E : NEGV;
  }

  // one DP step given this t's label-log2-probs
  auto step = [&](const float* lp) {
    float prev3 = __shfl_up(a[3], 1);     // state sbase-1
    float prev2 = __shfl_up(a[2], 1);     // state sbase-2
    prev3 = (lane == 0) ? NEGV : prev3;
    prev2 = (lane == 0) ? NEGV : prev2;
    float na[5];
#pragma unroll
    for (int j = 0; j < 5; j++) {
      float a1 = a[j];
      float a2 = (j >= 1) ? a[j - 1] : prev3;
      float v;
      if (j & 1) {                        // odd s: skip transition possible
        float a3 = (j >= 2) ? a[j - 2] : prev3;
        a3 = skf[j] ? a3 : NEGV;
        float m   = fmaxf(fmaxf(a1, a2), a3);
        float sum = fexp2(a1 - m) + fexp2(a2 - m) + fexp2(a3 - m);
        v = m + flog2(sum) + lp[j];
      } else {                            // even s (blank): never skips
        float m   = fmaxf(a1, a2);
        float sum = fexp2(a1 - m) + fexp2(a2 - m);
        v = m + flog2(sum) + lp[j];
      }
      na[j] = msk[j] ? v : NEGV;
    }
#pragma unroll
    for (int j = 0; j < 5; j++) a[j] = na[j];
  };

  // preload prefetch ring for t = 1..DPD
  float rlp[DPD][5];
#pragma unroll
  for (int d = 0; d < DPD; d++) {
    int tt = 1 + d;                        // < Tt always
#pragma unroll
    for (int j = 0; j < 5; j++)
      rlp[d][j] = ll[(size_t)tt * LS + eidx[j]] * L2E;
  }

  const int nfull = (hlen - 1) / DPD;      // full blocks of DPD steps from t=1
  for (int b = 0; b < nfull; b++) {
    const int t0 = 1 + b * DPD;
#pragma unroll
    for (int d = 0; d < DPD; d++) {
      float lp[5];
#pragma unroll
      for (int j = 0; j < 5; j++) lp[j] = rlp[d][j];
      int tn = t0 + d + DPD;
      if (tn > Tt - 1) tn = Tt - 1;        // clamp keeps loads in-bounds
#pragma unroll
      for (int j = 0; j < 5; j++)
        rlp[d][j] = ll[(size_t)tn * LS + eidx[j]] * L2E;
      step(lp);
    }
  }
  // tail (< DPD steps): direct loads, latency negligible
  for (int t = 1 + nfull * DPD; t < hlen; t++) {
    float lp[5];
#pragma unroll
    for (int j = 0; j < 5; j++) lp[j] = ll[(size_t)t * LS + eidx[j]] * L2E;
    step(lp);
  }

  __shared__ float alf[264];
#pragma unroll
  for (int j = 0; j < 4; j++) alf[sbase + j] = a[j];
  if (has5) alf[256] = a[4];
  __syncthreads();
  if (lane == 0) {
    float e1 = alf[Ln - 1];
    float e2 = alf[Ln - 2];
    float m  = fmaxf(e1, e2);
    float l2 = m + flog2(1.f + fexp2(fminf(e1, e2) - m));
    float llv = l2 * LN2 - slse;           // back to natural log, subtract lse sum
    float per = (llv > -1e29f) ? -llv : 0.f;
    atomicAdd(out, per * (1.0f / 16.0f));
  }
}

// ---------- launcher ----------
extern "C" void kernel_launch(void* const* d_in, const int* in_sizes, int n_in,
                              void* d_out, int out_size, void* d_ws, size_t ws_size,
                              hipStream_t stream) {
  const float* hs    = (const float*)d_in[0];
  const int*   hlens = (const int*)d_in[1];
  const int*   ys    = (const int*)d_in[2];
  const int*   ylens = (const int*)d_in[3];
  const float* W     = (const float*)d_in[4];
  const float* bias  = (const float*)d_in[5];
  float*       out   = (float*)d_out;
  char*        ws    = (char*)d_ws;

  // workspace carve (bytes)
  const size_t off_hsb    = 0;                               // 16,777,216
  const size_t off_Wb     = off_hsb    + (size_t)Nn*Tt*IDIM*2;
  const size_t off_lablog = off_Wb     + (size_t)Vv*IDIM*2;  // 8,650,752
  const size_t off_pmax   = off_lablog + (size_t)Nn*Tt*LS*4;
  const size_t off_psum   = off_pmax   + (size_t)64*16384*4;
  const size_t off_lse    = off_psum   + (size_t)64*16384*4;
  const size_t off_labmap = off_lse    + (size_t)16384*4;
  const size_t off_extidx = off_labmap + (size_t)Nn*Vv*4;
  const size_t off_skip   = off_extidx + (size_t)((Nn*Ll*4 + 255) & ~255);

  bfu16* hsb    = (bfu16*)(ws + off_hsb);
  bfu16* Wb     = (bfu16*)(ws + off_Wb);
  float* lablog = (float*)(ws + off_lablog);
  float* pmax   = (float*)(ws + off_pmax);
  float* psum   = (float*)(ws + off_psum);
  float* lse    = (float*)(ws + off_lse);
  int*   labmap = (int*)(ws + off_labmap);
  int*   extidx = (int*)(ws + off_extidx);
  int*   skipf  = (int*)(ws + off_skip);

  convert_zero<<<2048, 256, 0, stream>>>(
      (const float4*)hs, (const float4*)W, (ushort4*)hsb, (ushort4*)Wb, out);
  build_labels<<<16, 256, 0, stream>>>(ys, labmap, extidx, skipf);
  gemm_lse<<<dim3(128, 32), 256, 0, stream>>>(hsb, Wb, bias, labmap, lablog, pmax, psum);
  lse_reduce<<<64, 256, 0, stream>>>(pmax, psum, lse);
  ctc_dp<<<16, 64, 0, stream>>>(lablog, lse, extidx, skipf, hlens, ylens, out);
}

// Round 4
// 243.668 us; speedup vs baseline: 9.4581x; 1.3170x over previous
//
#include <hip/hip_runtime.h>
#include <cstdint>
#include <cstddef>

// ---------- types ----------
using short8_t = __attribute__((ext_vector_type(8))) short;
using f32x4    = __attribute__((ext_vector_type(4))) float;
typedef unsigned short bfu16;

constexpr int   Nn   = 16;
constexpr int   Tt   = 1024;
constexpr int   IDIM = 512;
constexpr int   Vv   = 4096;
constexpr int   Ss   = 128;
constexpr int   Ll   = 2 * Ss + 1;   // 257
constexpr int   LS   = 132;          // plab row stride (pad 129 -> 132)
constexpr float NEGV = -1e30f;
constexpr float L2E  = 1.4426950408889634f;  // log2(e)
constexpr float LN2  = 0.6931471805599453f;  // ln(2)

// ---------- helpers ----------
__device__ __forceinline__ float fexp2(float x) { return __builtin_amdgcn_exp2f(x); }
__device__ __forceinline__ float flog2(float x) { return __builtin_amdgcn_logf(x); }

__device__ __forceinline__ bfu16 f2bf(float f) {
  unsigned int x = __float_as_uint(f);
  x = x + 0x7fffu + ((x >> 16) & 1u);   // RNE (inputs are finite normals)
  return (bfu16)(x >> 16);
}

__device__ __forceinline__ void async16(const void* g, void* l) {
  __builtin_amdgcn_global_load_lds(
      (__attribute__((address_space(1))) void*)(g),
      (__attribute__((address_space(3))) void*)(l), 16, 0, 0);
}

// ---------- kernel 1: fp32 -> bf16 convert + zero output ----------
__global__ void convert_zero(const float4* __restrict__ hs4,
                             const float4* __restrict__ W4,
                             ushort4* __restrict__ hsb4,
                             ushort4* __restrict__ Wb4,
                             float* __restrict__ out) {
  if (blockIdx.x == 0 && threadIdx.x == 0) out[0] = 0.f;
  const int HS4 = (Nn * Tt * IDIM) / 4;        // 2097152
  const int TOT = HS4 + (Vv * IDIM) / 4;       // +524288
  for (int i = blockIdx.x * 256 + threadIdx.x; i < TOT; i += gridDim.x * 256) {
    float4 f;
    if (i < HS4) f = hs4[i]; else f = W4[i - HS4];
    ushort4 o;
    o.x = f2bf(f.x); o.y = f2bf(f.y); o.z = f2bf(f.z); o.w = f2bf(f.w);
    if (i < HS4) hsb4[i] = o; else Wb4[i - HS4] = o;
  }
}

// ---------- kernel 2: build label map / extended sequence ----------
__global__ void build_labels(const int* __restrict__ ys,
                             int* __restrict__ labmap,
                             int* __restrict__ extidx,
                             int* __restrict__ skipflag) {
  const int n = blockIdx.x, tid = threadIdx.x;
  int* lm = labmap + n * Vv;
  for (int v = tid; v < Vv; v += 256) lm[v] = 0x7fffffff;
  __syncthreads();
  if (tid == 0) lm[0] = 0;                                  // blank -> slot 0
  if (tid < Ss) atomicMin(&lm[ys[n * Ss + tid]], tid + 1);  // canonical = first occurrence
  __syncthreads();
  for (int s = tid; s < Ll; s += 256) {
    int v = (s & 1) ? ys[n * Ss + ((s - 1) >> 1)] : 0;
    extidx[n * Ll + s] = lm[v];
    int allow = 0;
    if ((s & 1) && s >= 3) allow = (v != ys[n * Ss + ((s - 3) >> 1)]) ? 1 : 0;
    skipflag[n * Ll + s] = allow;
  }
  __syncthreads();
  for (int v = tid; v < Vv; v += 256)
    if (lm[v] == 0x7fffffff) lm[v] = -1;
}

// ---------- kernel 3: bf16 MFMA GEMM fused with lse partials + label scatter ----------
// Label columns are stored as p = exp2(logit * log2e)  (linear domain for the DP).
__global__ __launch_bounds__(256) void gemm_lse(
    const bfu16* __restrict__ A,      // [16384][512] hs bf16
    const bfu16* __restrict__ B,      // [4096][512]  W  bf16 (B^T layout)
    const float* __restrict__ bias,   // [4096]
    const int*   __restrict__ labmap, // [16][4096]
    float* __restrict__ plab,         // [16384][LS]  exp2(logit*L2E) at label slots
    float* __restrict__ pmax,         // [64][16384]
    float* __restrict__ psum) {       // [64][16384]
  __shared__ bfu16 ldsA[128 * 32];    // 8 KB
  __shared__ bfu16 ldsB[128 * 32];    // 8 KB
  const int bR = blockIdx.x, bC = blockIdx.y;
  const int rowbase = bR * 128, colbase = bC * 128;
  const int tid  = threadIdx.x;
  const int lane = tid & 63, wid = tid >> 6;
  const int wr = wid >> 1, wc = wid & 1;

  f32x4 acc[4][4];
#pragma unroll
  for (int m = 0; m < 4; m++)
#pragma unroll
    for (int n = 0; n < 4; n++) {
      f32x4 z = {0.f, 0.f, 0.f, 0.f};
      acc[m][n] = z;
    }

  // staging: wave w owns rows [w*32, w*32+32) of each tile; 2 x 1KB issues per tile
  const int r16 = lane >> 2;              // 0..15
  const int cb  = (lane & 3) * 16;        // byte offset within 64B row
  const char* gA0 = (const char*)(A + (size_t)(rowbase + wid * 32 + r16) * IDIM) + cb;
  const char* gB0 = (const char*)(B + (size_t)(colbase + wid * 32 + r16) * IDIM) + cb;
  char* dA = (char*)ldsA + wid * 2048;
  char* dB = (char*)ldsB + wid * 2048;

  const int fr  = lane & 15;
  const int fkB = (lane >> 4) * 16;       // byte offset of lane's 8 contiguous k

  for (int k0 = 0; k0 < IDIM; k0 += 32) {
    const char* ga = gA0 + k0 * 2;
    const char* gb = gB0 + k0 * 2;
    async16(ga,          dA);
    async16(ga + 16384,  dA + 1024);      // +16 rows (16*512*2 bytes)
    async16(gb,          dB);
    async16(gb + 16384,  dB + 1024);
    __syncthreads();                      // drains vmcnt before reads

    short8_t af[4], bfr[4];
#pragma unroll
    for (int m = 0; m < 4; m++)
      af[m] = *(const short8_t*)((const char*)ldsA + (wr * 64 + m * 16 + fr) * 64 + fkB);
#pragma unroll
    for (int n = 0; n < 4; n++)
      bfr[n] = *(const short8_t*)((const char*)ldsB + (wc * 64 + n * 16 + fr) * 64 + fkB);

#pragma unroll
    for (int m = 0; m < 4; m++)
#pragma unroll
      for (int n = 0; n < 4; n++)
        acc[m][n] = __builtin_amdgcn_mfma_f32_16x16x32_bf16(af[m], bfr[n], acc[m][n], 0, 0, 0);
    __syncthreads();                      // protect LDS before next stage
  }

  // ---- epilogue: bias, label scatter (exp2'd), row-wise max/sumexp partials ----
  const int nsamp = bR >> 3;              // 8 row-tiles per sample
  const int* lm = labmap + nsamp * Vv;
  const int g4 = (lane >> 4) * 4;

  float bc[4];
  int   slot[4];
#pragma unroll
  for (int n = 0; n < 4; n++) {
    int c = colbase + wc * 64 + n * 16 + fr;
    bc[n]   = bias[c];
    slot[n] = lm[c];
  }

#pragma unroll
  for (int m = 0; m < 4; m++) {
#pragma unroll
    for (int r = 0; r < 4; r++) {
      int row = rowbase + wr * 64 + m * 16 + g4 + r;
      float v0 = acc[m][0][r] + bc[0];
      float v1 = acc[m][1][r] + bc[1];
      float v2 = acc[m][2][r] + bc[2];
      float v3 = acc[m][3][r] + bc[3];
      if (slot[0] >= 0) plab[(size_t)row * LS + slot[0]] = fexp2(v0 * L2E);
      if (slot[1] >= 0) plab[(size_t)row * LS + slot[1]] = fexp2(v1 * L2E);
      if (slot[2] >= 0) plab[(size_t)row * LS + slot[2]] = fexp2(v2 * L2E);
      if (slot[3] >= 0) plab[(size_t)row * LS + slot[3]] = fexp2(v3 * L2E);
      float mx = fmaxf(fmaxf(v0, v1), fmaxf(v2, v3));
      float sm = __expf(v0 - mx) + __expf(v1 - mx) + __expf(v2 - mx) + __expf(v3 - mx);
#pragma unroll
      for (int off = 1; off < 16; off <<= 1) {
        float om = __shfl_xor(mx, off);
        float os = __shfl_xor(sm, off);
        float nm = fmaxf(mx, om);
        sm = sm * __expf(mx - nm) + os * __expf(om - nm);
        mx = nm;
      }
      if (fr == 0) {
        int pc = bC * 2 + wc;             // 0..63
        pmax[(size_t)pc * 16384 + row] = mx;
        psum[(size_t)pc * 16384 + row] = sm;
      }
    }
  }
}

// ---------- kernel 4: reduce 64 lse partials per row ----------
__global__ void lse_reduce(const float* __restrict__ pmax,
                           const float* __restrict__ psum,
                           float* __restrict__ lse) {
  int row = blockIdx.x * 256 + threadIdx.x;
  float m = NEGV, s = 0.f;
#pragma unroll 8
  for (int j = 0; j < 64; j++) {
    float pm = pmax[(size_t)j * 16384 + row];
    float ps = psum[(size_t)j * 16384 + row];
    float nm = fmaxf(m, pm);
    s = s * __expf(m - nm) + ps * __expf(pm - nm);
    m = nm;
  }
  lse[row] = m + __logf(s);
}

// ---------- kernel 5: CTC forward DP, one wave per sample ----------
// LINEAR-domain DP on raw-logit probabilities p = 2^(logit*L2E), with
// wave-uniform power-of-2 rescaling every 16 steps. Zero transcendentals
// in the serial loop. lse correction applied once at the end.
constexpr int DPD = 8;   // prefetch depth

__global__ __launch_bounds__(64) void ctc_dp(
    const float* __restrict__ plab, const float* __restrict__ lse,
    const int* __restrict__ extidx, const int* __restrict__ skipflag,
    const int* __restrict__ hlens, const int* __restrict__ ylens,
    float* __restrict__ out) {
  const int n    = blockIdx.x;
  const int lane = threadIdx.x;
  const int hlen = hlens[n];
  const int Ln   = 2 * ylens[n] + 1;
  const int sbase = lane * 4;   // states sbase..sbase+3; lane 63 also owns s=256

  // per-lane static DP metadata (even states are blanks since sbase is even)
  const int   e1  = extidx[n * Ll + sbase + 1];
  const int   e3  = extidx[n * Ll + sbase + 3];
  const float sk1 = skipflag[n * Ll + sbase + 1] ? 1.f : 0.f;
  const float sk3 = skipflag[n * Ll + sbase + 3] ? 1.f : 0.f;
  const float m0  = (sbase + 0 < Ln) ? 1.f : 0.f;
  const float m1  = (sbase + 1 < Ln) ? 1.f : 0.f;
  const float m2  = (sbase + 2 < Ln) ? 1.f : 0.f;
  const float m3  = (sbase + 3 < Ln) ? 1.f : 0.f;
  const float m4  = (lane == 63 && Ln == 257) ? 1.f : 0.f;

  const float* pl  = plab + (size_t)n * Tt * LS;
  const float* lsp = lse + n * Tt;

  // sum of lse over t < hlen (uniform across states -> applied once at end)
  float slse = 0.f;
  for (int t = lane; t < hlen; t += 64) slse += lsp[t];
#pragma unroll
  for (int off = 32; off; off >>= 1) slse += __shfl_xor(slse, off);

  // t = 0 init: alpha[0] = p_blank(0), alpha[1] = p_y1(0)
  float a0 = 0.f, a1 = 0.f, a2 = 0.f, a3 = 0.f, a4 = 0.f;
  if (lane == 0) { a0 = pl[0]; a1 = pl[e1]; }

  int sc = 0;   // accumulated log2 scale (true alpha = stored * 2^sc)

  auto step = [&](float pb, float p1, float p3) {
    float pm1 = __shfl_up(a3, 1);      // alpha[sbase-1]
    float pm2 = __shfl_up(a2, 1);      // alpha[sbase-2]
    pm1 = (lane == 0) ? 0.f : pm1;
    pm2 = (lane == 0) ? 0.f : pm2;
    float n4 = (a4 + a3) * pb * m4;                 // s=256 (blank), lane 63 only
    float n3 = (a3 + a2 + sk3 * a1)  * p3 * m3;     // odd (label)
    float n2 = (a2 + a1)             * pb * m2;     // even (blank)
    float n1 = (a1 + a0 + sk1 * pm2) * p1 * m1;     // odd (label)
    float n0 = (a0 + pm1)            * pb * m0;     // even (blank)
    a0 = n0; a1 = n1; a2 = n2; a3 = n3; a4 = n4;
  };

  auto rescale = [&]() {
    float mx = fmaxf(fmaxf(a0, a1), fmaxf(a2, a3));
    mx = fmaxf(mx, a4);
#pragma unroll
    for (int off = 32; off; off >>= 1) mx = fmaxf(mx, __shfl_xor(mx, off));
    int ee = (int)((__float_as_uint(mx) >> 23) & 0xff) - 127;   // floor(log2 mx)
    ee = (mx > 0.f) ? ee : 0;
    float s = __uint_as_float((unsigned)(127 - ee) << 23);      // 2^(-ee)
    sc += ee;
    a0 *= s; a1 *= s; a2 *= s; a3 *= s; a4 *= s;
  };

  // preload prefetch ring for t = 1..DPD (1 uniform blank + 2 gathers per row)
  float rb[DPD], r1[DPD], r3[DPD];
#pragma unroll
  for (int d = 0; d < DPD; d++) {
    int tt = 1 + d;
    rb[d] = pl[(size_t)tt * LS];
    r1[d] = pl[(size_t)tt * LS + e1];
    r3[d] = pl[(size_t)tt * LS + e3];
  }

  const int nfull = (hlen - 1) / DPD;
  for (int b = 0; b < nfull; b++) {
    const int t0 = 1 + b * DPD;
#pragma unroll
    for (int d = 0; d < DPD; d++) {
      float pb = rb[d], p1 = r1[d], p3 = r3[d];
      int tn = t0 + d + DPD;
      if (tn > Tt - 1) tn = Tt - 1;    // clamp keeps loads in-bounds
      rb[d] = pl[(size_t)tn * LS];
      r1[d] = pl[(size_t)tn * LS + e1];
      r3[d] = pl[(size_t)tn * LS + e3];
      step(pb, p1, p3);
    }
    if ((b & 1) || b == nfull - 1) rescale();   // every 16 steps + final block
  }
  // tail (< DPD steps): direct loads
  for (int t = 1 + nfull * DPD; t < hlen; t++) {
    step(pl[(size_t)t * LS], pl[(size_t)t * LS + e1], pl[(size_t)t * LS + e3]);
  }

  __shared__ float alf[264];
  alf[sbase + 0] = a0; alf[sbase + 1] = a1;
  alf[sbase + 2] = a2; alf[sbase + 3] = a3;
  if (lane == 63) alf[256] = a4;
  __syncthreads();
  if (lane == 0) {
    float sum = alf[Ln - 1] + alf[Ln - 2];
    float per = 0.f;
    if (sum > 0.f) {
      float llv = (flog2(sum) + (float)sc) * LN2 - slse;
      if (llv > -1e29f) per = -llv;
    }
    atomicAdd(out, per * (1.0f / 16.0f));
  }
}

// ---------- launcher ----------
extern "C" void kernel_launch(void* const* d_in, const int* in_sizes, int n_in,
                              void* d_out, int out_size, void* d_ws, size_t ws_size,
                              hipStream_t stream) {
  const float* hs    = (const float*)d_in[0];
  const int*   hlens = (const int*)d_in[1];
  const int*   ys    = (const int*)d_in[2];
  const int*   ylens = (const int*)d_in[3];
  const float* W     = (const float*)d_in[4];
  const float* bias  = (const float*)d_in[5];
  float*       out   = (float*)d_out;
  char*        ws    = (char*)d_ws;

  // workspace carve (bytes)
  const size_t off_hsb    = 0;                               // 16,777,216
  const size_t off_Wb     = off_hsb    + (size_t)Nn*Tt*IDIM*2;
  const size_t off_plab   = off_Wb     + (size_t)Vv*IDIM*2;  // 8,650,752
  const size_t off_pmax   = off_plab   + (size_t)Nn*Tt*LS*4;
  const size_t off_psum   = off_pmax   + (size_t)64*16384*4;
  const size_t off_lse    = off_psum   + (size_t)64*16384*4;
  const size_t off_labmap = off_lse    + (size_t)16384*4;
  const size_t off_extidx = off_labmap + (size_t)Nn*Vv*4;
  const size_t off_skip   = off_extidx + (size_t)((Nn*Ll*4 + 255) & ~255);

  bfu16* hsb    = (bfu16*)(ws + off_hsb);
  bfu16* Wb     = (bfu16*)(ws + off_Wb);
  float* plab   = (float*)(ws + off_plab);
  float* pmax   = (float*)(ws + off_pmax);
  float* psum   = (float*)(ws + off_psum);
  float* lse    = (float*)(ws + off_lse);
  int*   labmap = (int*)(ws + off_labmap);
  int*   extidx = (int*)(ws + off_extidx);
  int*   skipf  = (int*)(ws + off_skip);

  convert_zero<<<2048, 256, 0, stream>>>(
      (const float4*)hs, (const float4*)W, (ushort4*)hsb, (ushort4*)Wb, out);
  build_labels<<<16, 256, 0, stream>>>(ys, labmap, extidx, skipf);
  gemm_lse<<<dim3(128, 32), 256, 0, stream>>>(hsb, Wb, bias, labmap, plab, pmax, psum);
  lse_reduce<<<64, 256, 0, stream>>>(pmax, psum, lse);
  ctc_dp<<<16, 64, 0, stream>>>(plab, lse, extidx, skipf, hlens, ylens, out);
}